// Round 1
// baseline (323.102 us; speedup 1.0000x reference)
//
#include <hip/hip_runtime.h>

// Problem constants (fixed by setup_inputs)
#define N_ROWS 65536
#define KDIM   256
#define CM     190      // C*M = 19*10
#define CMP    192      // padded to 12 x 16-col tiles
#define KP     512      // concatenated K: [xbar | sqrt_xv]
#define LAMDA  (1.0f/64.0f)
#define LN_EPS 1e-5f

typedef __bf16 bf16;
typedef __attribute__((ext_vector_type(4))) __bf16 bf16x4;
typedef __attribute__((ext_vector_type(8))) __bf16 bf16x8;
typedef __attribute__((ext_vector_type(4))) float  f32x4;

// 64-lane butterfly reduction
__device__ __forceinline__ float wred(float v) {
#pragma unroll
    for (int o = 32; o > 0; o >>= 1) v += __shfl_xor(v, o, 64);
    return v;
}

// Store 4 consecutive bf16 (kp 4-aligned) of element-row rr within 16-tile
// `tile`, into MFMA fragment-linear layout:
//   lane L of the wave reading (tile, ks) grabs 16B at ((tile*16+ks)*64+L)*8.
// Element (rr, kp): ks=kp>>5, kk=kp&31, L = rr | ((kk>>3)<<4), j = kk&7.
__device__ __forceinline__ void frag_store4(bf16* frag, int tile, int rr, int kp,
                                            float a, float b, float c, float d) {
    int ks = kp >> 5;
    int kk = kp & 31;
    int L  = rr | ((kk >> 3) << 4);
    int j  = kk & 7;
    bf16x4 pk;
    pk[0] = (bf16)a; pk[1] = (bf16)b; pk[2] = (bf16)c; pk[3] = (bf16)d;
    *(bf16x4*)(frag + ((tile * 16 + ks) * 64 + L) * 8 + j) = pk;
}

// Shared row math: reparameterize 2 samples, layer_norm, l2_normalize, average.
// Lane holds elements k0..k0+3 of a 256-length row. Outputs:
//   xb[4]   = 0.5*(ls(l2(s0)) + ls(l2(s1)))   (this lane's 4 elems)
//   sx[4]   = exp(0.5*logvar)
//   sum_ev  = sum_k exp(logvar)   (wave-uniform)
__device__ __forceinline__ void row_prep(const float4& X, const float4& V,
                                         const float4& E0, const float4& E1,
                                         const float* w, const float* b,
                                         float* xb, float* sx, float& sum_ev) {
    float xx[4] = {X.x, X.y, X.z, X.w};
    float vv[4] = {V.x, V.y, V.z, V.w};
    float e0[4] = {E0.x, E0.y, E0.z, E0.w};
    float e1[4] = {E1.x, E1.y, E1.z, E1.w};
    sum_ev = 0.0f;
#pragma unroll
    for (int t = 0; t < 4; t++) {
        sx[t] = __expf(0.5f * vv[t]);
        sum_ev += sx[t] * sx[t];       // exp(v) = exp(0.5v)^2
    }
    sum_ev = wred(sum_ev);
    xb[0] = xb[1] = xb[2] = xb[3] = 0.0f;
#pragma unroll
    for (int r = 0; r < 2; r++) {
        const float* e = r ? e1 : e0;
        float tt[4], s1 = 0.0f, s2 = 0.0f;
#pragma unroll
        for (int t = 0; t < 4; t++) {
            tt[t] = e[t] * sx[t] + xx[t];
            s1 += tt[t];
            s2 += tt[t] * tt[t];
        }
        s1 = wred(s1); s2 = wred(s2);
        float mu  = s1 * (1.0f / 256.0f);
        float var = s2 * (1.0f / 256.0f) - mu * mu;
        float inv = rsqrtf(var + LN_EPS);
        float y[4], n2 = 0.0f;
#pragma unroll
        for (int t = 0; t < 4; t++) {
            y[t] = (tt[t] - mu) * inv * w[t] + b[t];
            n2 += y[t] * y[t];
        }
        n2 = wred(n2);
        float sc = 1.0f / fmaxf(sqrtf(n2), 1e-12f);
#pragma unroll
        for (int t = 0; t < 4; t++) xb[t] += 0.5f * y[t] * sc;
    }
}

// ---------------- Kernel 1: prototype prep -> B' fragments + bias_cm --------
// B'[cm, k<256]  = 2 * pbar[k]          (covers  2*mean sim)
// B'[cm, 256+k]  = 2*lamda*exp(0.5*pv)  (covers  2*lamda*cross)
// bias_cm[cm]    = -lamda * sum_k exp(pv)
__global__ void __launch_bounds__(64) proto_prep(
        const float* __restrict__ proto, const float* __restrict__ pvar,
        const float* __restrict__ eps_p, const float* __restrict__ ln_w,
        const float* __restrict__ ln_b, bf16* __restrict__ Bfrag,
        float* __restrict__ bias_cm) {
    int cm = blockIdx.x;            // 0..191 (190,191 are zero pad)
    int lane = threadIdx.x;         // 0..63
    int ct = cm >> 4, rr = cm & 15;
    int k0 = lane * 4;
    if (cm >= CM) {
        frag_store4(Bfrag, ct, rr, k0,       0.f, 0.f, 0.f, 0.f);
        frag_store4(Bfrag, ct, rr, 256 + k0, 0.f, 0.f, 0.f, 0.f);
        if (lane == 0) bias_cm[cm] = 0.0f;
        return;
    }
    size_t roff = (size_t)cm * KDIM + k0;
    float4 P  = *(const float4*)(proto + roff);
    float4 V  = *(const float4*)(pvar + roff);
    float4 E0 = *(const float4*)(eps_p + roff);
    float4 E1 = *(const float4*)(eps_p + (size_t)CM * KDIM + roff);
    float4 Wv = *(const float4*)(ln_w + k0);
    float4 Bv = *(const float4*)(ln_b + k0);
    float w[4] = {Wv.x, Wv.y, Wv.z, Wv.w};
    float b[4] = {Bv.x, Bv.y, Bv.z, Bv.w};
    float pb[4], sx[4], sum_ev;
    row_prep(P, V, E0, E1, w, b, pb, sx, sum_ev);
    frag_store4(Bfrag, ct, rr, k0, 2.f * pb[0], 2.f * pb[1], 2.f * pb[2], 2.f * pb[3]);
    frag_store4(Bfrag, ct, rr, 256 + k0, 2.f * LAMDA * sx[0], 2.f * LAMDA * sx[1],
                2.f * LAMDA * sx[2], 2.f * LAMDA * sx[3]);
    if (lane == 0) bias_cm[cm] = -LAMDA * sum_ev;
}

// ---------------- Kernel 2: fused x-prep + GEMM + epilogue ------------------
// Block = 256 threads (4 waves), 64 N-rows. Phase 1: each wave LN+L2-norms its
// 16 rows, writes A' fragments (fragment-linear) to LDS. Phase 2: MFMA
// 16x16x32 bf16; wave w computes col-tiles 3w..3w+2 for all 4 row-tiles.
// out[n, cm] = dot(A'[n], B'[cm]) + bias_n[n] + bias_cm[cm] - 2
__global__ void __launch_bounds__(256) fused_main(
        const float* __restrict__ x, const float* __restrict__ xvar,
        const float* __restrict__ eps_x, const float* __restrict__ ln_w,
        const float* __restrict__ ln_b, const bf16* __restrict__ Bfrag,
        const float* __restrict__ bias_cm, float* __restrict__ out) {
    __shared__ bf16 Afrag[64 * KP];     // 64 KB, fragment-linear
    __shared__ float bias_n_s[64];
    int tid = threadIdx.x;
    int wave = tid >> 6, lane = tid & 63;
    int row0 = blockIdx.x * 64;
    int k0 = lane * 4;
    float4 Wv = *(const float4*)(ln_w + k0);
    float4 Bv = *(const float4*)(ln_b + k0);
    float w[4] = {Wv.x, Wv.y, Wv.z, Wv.w};
    float b[4] = {Bv.x, Bv.y, Bv.z, Bv.w};

    // ---- phase 1: prep 16 rows per wave ----
#pragma unroll 1
    for (int rr = 0; rr < 16; rr++) {
        int lr = wave * 16 + rr;
        size_t roff = (size_t)(row0 + lr) * KDIM + k0;
        float4 X  = *(const float4*)(x + roff);
        float4 V  = *(const float4*)(xvar + roff);
        float4 E0 = *(const float4*)(eps_x + roff);
        float4 E1 = *(const float4*)(eps_x + (size_t)N_ROWS * KDIM + roff);
        float xb[4], sx[4], sum_ev;
        row_prep(X, V, E0, E1, w, b, xb, sx, sum_ev);
        if (lane == 0) bias_n_s[lr] = -LAMDA * sum_ev;
        frag_store4(Afrag, wave, rr, k0, xb[0], xb[1], xb[2], xb[3]);
        frag_store4(Afrag, wave, rr, 256 + k0, sx[0], sx[1], sx[2], sx[3]);
    }
    __syncthreads();

    // ---- phase 2: GEMM ----
    f32x4 acc[3][4];
#pragma unroll
    for (int c = 0; c < 3; c++)
#pragma unroll
        for (int r = 0; r < 4; r++) acc[c][r] = (f32x4){0.f, 0.f, 0.f, 0.f};

#pragma unroll 1
    for (int ks = 0; ks < 16; ks++) {
        bf16x8 a[4];
#pragma unroll
        for (int rt = 0; rt < 4; rt++)
            a[rt] = *(const bf16x8*)(Afrag + ((rt * 16 + ks) * 64 + lane) * 8);
#pragma unroll
        for (int ctl = 0; ctl < 3; ctl++) {
            int ct = wave * 3 + ctl;
            bf16x8 bb = *(const bf16x8*)(Bfrag + ((ct * 16 + ks) * 64 + lane) * 8);
#pragma unroll
            for (int rt = 0; rt < 4; rt++)
                acc[ctl][rt] = __builtin_amdgcn_mfma_f32_16x16x32_bf16(a[rt], bb, acc[ctl][rt], 0, 0, 0);
        }
    }

    // ---- epilogue: D layout col=lane&15, row=(lane>>4)*4+reg ----
#pragma unroll
    for (int ctl = 0; ctl < 3; ctl++) {
        int col = wave * 48 + ctl * 16 + (lane & 15);
        float bcm = bias_cm[col];
        bool ok = (col < CM);
#pragma unroll
        for (int rt = 0; rt < 4; rt++) {
            int lr0 = rt * 16 + ((lane >> 4) << 2);
#pragma unroll
            for (int reg = 0; reg < 4; reg++) {
                int lr = lr0 + reg;
                if (ok)
                    out[(size_t)(row0 + lr) * CM + col] =
                        acc[ctl][rt][reg] + bias_n_s[lr] + bcm - 2.0f;
            }
        }
    }
}

extern "C" void kernel_launch(void* const* d_in, const int* in_sizes, int n_in,
                              void* d_out, int out_size, void* d_ws, size_t ws_size,
                              hipStream_t stream) {
    const float* x     = (const float*)d_in[0];
    const float* xvar  = (const float*)d_in[1];
    const float* proto = (const float*)d_in[2];
    const float* pvar  = (const float*)d_in[3];
    const float* eps_x = (const float*)d_in[4];
    const float* eps_p = (const float*)d_in[5];
    const float* ln_w  = (const float*)d_in[6];
    const float* ln_b  = (const float*)d_in[7];
    float* out = (float*)d_out;

    bf16*  Bfrag   = (bf16*)d_ws;                                   // 192*512*2 B
    float* bias_cm = (float*)((char*)d_ws + (size_t)CMP * KP * 2);  // 192 floats

    proto_prep<<<CMP, 64, 0, stream>>>(proto, pvar, eps_p, ln_w, ln_b, Bfrag, bias_cm);
    fused_main<<<N_ROWS / 64, 256, 0, stream>>>(x, xvar, eps_x, ln_w, ln_b, Bfrag, bias_cm, out);
}